// Round 4
// baseline (644.411 us; speedup 1.0000x reference)
//
#include <hip/hip_runtime.h>
#include <math.h>

// Problem: B=64, S=2048, H=1024. Single-query attention + concat.
// out[b, 0:H]  = h_n[b]
// out[b, H:2H] = softmax_s(h_n[b]·enc[b,s,:]) @ enc[b,:,:]
//
// Memory-bound: enc is 537 MB, read once. Partial kernel was ~300us
// (~1.8 TB/s, 28% of achievable). Theory: per-wave memory convoy --
// 4 loads then vmcnt(0) + ~400cy butterfly/softmax with ZERO bytes in
// flight. v4: explicit A/B register double-buffer (next pair's 8 loads
// issued before current pair is consumed => partial vmcnt waits, 8KB+
// continuously in flight per wave) + interleaved 2-row butterflies +
// LAZY rescale (only rescale acc when running max grows: ~4-5 times per
// 32 rows instead of every row -- shortens the non-VMEM phase).
// Keeps round-3's start-row rotation + nontemporal loads (+34us proven).

#define BB 64
#define SS 2048
#define HH 1024
#define NCHUNK 16              // S-chunks per batch -> 64*16 = 1024 blocks
#define SCHUNK (SS / NCHUNK)   // 128 rows per block
#define NWAVE 4                // 256 threads
#define NPAIR (SCHUNK / (2 * NWAVE))   // 16 row-pairs per wave

typedef float fvec4 __attribute__((ext_vector_type(4)));

// ws layout:
//   [0 .. B*NCHUNK*H)              : partial ctx accumulators (float)
//   [B*NCHUNK*H .. +B*NCHUNK*2)    : (m, l) pairs per partial
#define WS_ML_OFF ((size_t)BB * NCHUNK * HH)

// load row-pair kk (this wave's kk-th pair) into register buffers E0,E1
#define LOADP(kk, E0, E1) do {                                              \
    const int pp_ = wave + NWAVE * (kk);                                    \
    const int r0_ = (start + 2 * pp_)     & (SCHUNK - 1);                   \
    const int r1_ = (start + 2 * pp_ + 1) & (SCHUNK - 1);                   \
    const fvec4* R0_ = enc4 + (size_t)(s0 + r0_) * (HH / 4);                \
    const fvec4* R1_ = enc4 + (size_t)(s0 + r1_) * (HH / 4);                \
    _Pragma("unroll")                                                       \
    for (int j = 0; j < 4; ++j) {                                           \
        E0[j] = __builtin_nontemporal_load(&R0_[j * 64 + lane]);            \
        E1[j] = __builtin_nontemporal_load(&R1_[j * 64 + lane]);            \
    }                                                                       \
} while (0)

#define DOT4(E, j) (E[j].x * h4[j].x + E[j].y * h4[j].y                     \
                  + E[j].z * h4[j].z + E[j].w * h4[j].w)

// consume one row-pair: dot, interleaved butterfly, lazy-rescale softmax
#define CONSUME(E0, E1) do {                                                \
    float d0_ = DOT4(E0, 0) + DOT4(E0, 1) + DOT4(E0, 2) + DOT4(E0, 3);     \
    float d1_ = DOT4(E1, 0) + DOT4(E1, 1) + DOT4(E1, 2) + DOT4(E1, 3);     \
    _Pragma("unroll")                                                       \
    for (int off_ = 32; off_ > 0; off_ >>= 1) {                             \
        d0_ += __shfl_xor(d0_, off_, 64);                                   \
        d1_ += __shfl_xor(d1_, off_, 64);                                   \
    }                                                                       \
    const float pm_ = fmaxf(d0_, d1_);                                      \
    if (pm_ <= m) {            /* common path: max unchanged, no rescale */ \
        const float p0_ = __expf(d0_ - m);                                  \
        const float p1_ = __expf(d1_ - m);                                  \
        l += p0_ + p1_;                                                     \
        _Pragma("unroll")                                                   \
        for (int j = 0; j < 4; ++j) {                                       \
            acc[j].x = fmaf(p0_, E0[j].x, fmaf(p1_, E1[j].x, acc[j].x));    \
            acc[j].y = fmaf(p0_, E0[j].y, fmaf(p1_, E1[j].y, acc[j].y));    \
            acc[j].z = fmaf(p0_, E0[j].z, fmaf(p1_, E1[j].z, acc[j].z));    \
            acc[j].w = fmaf(p0_, E0[j].w, fmaf(p1_, E1[j].w, acc[j].w));    \
        }                                                                   \
    } else {                   /* rare path: max grew, rescale acc and l */ \
        const float sc_ = __expf(m - pm_);   /* first iter: exp(-inf)=0 */  \
        const float p0_ = __expf(d0_ - pm_);                                \
        const float p1_ = __expf(d1_ - pm_);                                \
        l = l * sc_ + p0_ + p1_;                                            \
        m = pm_;                                                            \
        _Pragma("unroll")                                                   \
        for (int j = 0; j < 4; ++j) {                                       \
            acc[j].x = fmaf(acc[j].x, sc_, fmaf(p0_, E0[j].x, p1_ * E1[j].x)); \
            acc[j].y = fmaf(acc[j].y, sc_, fmaf(p0_, E0[j].y, p1_ * E1[j].y)); \
            acc[j].z = fmaf(acc[j].z, sc_, fmaf(p0_, E0[j].z, p1_ * E1[j].z)); \
            acc[j].w = fmaf(acc[j].w, sc_, fmaf(p0_, E0[j].w, p1_ * E1[j].w)); \
        }                                                                   \
    }                                                                       \
} while (0)

__global__ __launch_bounds__(256) void attn_partial_kernel(
    const float* __restrict__ enc, const float* __restrict__ hn,
    float* __restrict__ ws)
{
    const int blk   = blockIdx.x;          // b * NCHUNK + chunk
    const int b     = blk / NCHUNK;
    const int chunk = blk % NCHUNK;
    const int tid   = threadIdx.x;
    const int wave  = tid >> 6;
    const int lane  = tid & 63;

    // Preload this lane's 16 h_n elements
    const fvec4* hn4 = (const fvec4*)(hn + (size_t)b * HH);
    fvec4 h4[4];
#pragma unroll
    for (int j = 0; j < 4; ++j) h4[j] = hn4[j * 64 + lane];

    const fvec4* enc4 = (const fvec4*)(enc + (size_t)b * SS * HH);

    float m = -INFINITY;
    float l = 0.0f;
    fvec4 acc[4];
#pragma unroll
    for (int j = 0; j < 4; ++j) acc[j] = (fvec4)(0.f, 0.f, 0.f, 0.f);

    const int s0    = chunk * SCHUNK;
    const int start = (blk * 53) & (SCHUNK - 1);   // per-block phase rotation

    // ---- software-pipelined main loop: A/B register double buffer ----
    fvec4 eA0[4], eA1[4], eB0[4], eB1[4];

    LOADP(0, eA0, eA1);
#pragma unroll
    for (int k = 0; k < NPAIR / 2 - 1; ++k) {      // k = 0..6
        LOADP(2 * k + 1, eB0, eB1);
        CONSUME(eA0, eA1);
        LOADP(2 * k + 2, eA0, eA1);
        CONSUME(eB0, eB1);
    }
    LOADP(NPAIR - 1, eB0, eB1);
    CONSUME(eA0, eA1);
    CONSUME(eB0, eB1);

    // ---- combine 4 wave-partials within the block via LDS ----
    __shared__ float s_m[NWAVE];
    __shared__ float s_l[NWAVE];
    __shared__ float s_acc[NWAVE][HH];     // 16 KB

#pragma unroll
    for (int j = 0; j < 4; ++j)
        ((fvec4*)s_acc[wave])[j * 64 + lane] = acc[j];
    if (lane == 0) { s_m[wave] = m; s_l[wave] = l; }
    __syncthreads();

    float M = fmaxf(fmaxf(s_m[0], s_m[1]), fmaxf(s_m[2], s_m[3]));
    float sc[NWAVE];
    float L = 0.0f;
#pragma unroll
    for (int w = 0; w < NWAVE; ++w) {
        sc[w] = __expf(s_m[w] - M);
        L += s_l[w] * sc[w];
    }

    fvec4 ctx = (fvec4)(0.f, 0.f, 0.f, 0.f);
#pragma unroll
    for (int w = 0; w < NWAVE; ++w) {
        fvec4 a = ((const fvec4*)s_acc[w])[tid];
        ctx.x += sc[w] * a.x;  ctx.y += sc[w] * a.y;
        ctx.z += sc[w] * a.z;  ctx.w += sc[w] * a.w;
    }
    ((fvec4*)(ws + (size_t)blk * HH))[tid] = ctx;
    if (tid == 0) {
        ws[WS_ML_OFF + (size_t)blk * 2 + 0] = M;
        ws[WS_ML_OFF + (size_t)blk * 2 + 1] = L;
    }
}

__global__ __launch_bounds__(256) void attn_final_kernel(
    const float* __restrict__ hn, const float* __restrict__ ws,
    float* __restrict__ out)
{
    const int b   = blockIdx.x;
    const int tid = threadIdx.x;
    const float* ml = ws + WS_ML_OFF + (size_t)b * NCHUNK * 2;

    float M = -INFINITY;
#pragma unroll
    for (int c = 0; c < NCHUNK; ++c) M = fmaxf(M, ml[c * 2]);

    float sc[NCHUNK];
    float T = 0.0f;
#pragma unroll
    for (int c = 0; c < NCHUNK; ++c) {
        sc[c] = __expf(ml[c * 2] - M);
        T += sc[c] * ml[c * 2 + 1];
    }
    const float invT = 1.0f / T;

    fvec4 ctx = (fvec4)(0.f, 0.f, 0.f, 0.f);
#pragma unroll
    for (int c = 0; c < NCHUNK; ++c) {
        fvec4 a = ((const fvec4*)(ws + (size_t)(b * NCHUNK + c) * HH))[tid];
        ctx.x += sc[c] * a.x;  ctx.y += sc[c] * a.y;
        ctx.z += sc[c] * a.z;  ctx.w += sc[c] * a.w;
    }
    ctx.x *= invT; ctx.y *= invT; ctx.z *= invT; ctx.w *= invT;

    const fvec4 dec = ((const fvec4*)(hn + (size_t)b * HH))[tid];
    fvec4* o = (fvec4*)(out + (size_t)b * 2 * HH);
    o[tid]            = dec;   // dec_output half
    o[tid + (HH / 4)] = ctx;   // context half
}

extern "C" void kernel_launch(void* const* d_in, const int* in_sizes, int n_in,
                              void* d_out, int out_size, void* d_ws, size_t ws_size,
                              hipStream_t stream) {
    const float* enc = (const float*)d_in[0];   // (B, S, H) fp32
    const float* hn  = (const float*)d_in[1];   // (B, H) fp32
    float* out = (float*)d_out;                 // (B, 1, 2H) fp32
    float* ws  = (float*)d_ws;

    attn_partial_kernel<<<dim3(BB * NCHUNK), dim3(256), 0, stream>>>(enc, hn, ws);
    attn_final_kernel<<<dim3(BB), dim3(256), 0, stream>>>(hn, ws, out);
}